// Round 16
// baseline (130.934 us; speedup 1.0000x reference)
//
#include <hip/hip_runtime.h>
#include <hip/hip_bf16.h>
#include <stdint.h>

// Problem dims (fixed by reference setup_inputs)
#define B_SZ 128
#define R_SZ 36       // real regions per image
#define RP_SZ 48      // padded regions (dup row 35) -> multiple of 16
#define W_SZ 60       // real words per caption
#define WP_SZ 64      // padded words (dup word 59, masked in epilogue)
#define D_SZ 1024
#define MARGIN 0.2f

#define ATILE_B (192 * 64)   // BYTES per A K-tile (fp8, BK=64)
#define BTILE_B (256 * 64)   // BYTES per B K-tile

typedef __attribute__((ext_vector_type(4))) float f32x4;    // MFMA C/D frag
typedef __attribute__((ext_vector_type(2))) long longx2;    // one b128 = 2 fp8 frags

typedef __attribute__((address_space(3))) unsigned int lds_u32;
typedef const __attribute__((address_space(1))) unsigned int glb_u32;

__device__ __forceinline__ void gload16(const unsigned char* g, unsigned char* l) {
    __builtin_amdgcn_global_load_lds((glb_u32*)g, (lds_u32*)l, 16, 0, 0);
}

// fp32 -> fp8 e4m3 (HW cvt) + row-pad + K2-INTERLEAVE (validated R14/R15).
// Each 64-B K-block of a row stored as [granule g=kgrp][k2][8B]:
//   out byte g*16 + k2*8 + b  <=  original k = k2*32 + g*8 + b.
__global__ __launch_bounds__(256) void convert_fp8_kernel(
        const float* __restrict__ im, const float* __restrict__ s,
        unsigned char* __restrict__ imb, unsigned char* __restrict__ sb) {
    const int nA = B_SZ * RP_SZ * 64;     // 16-B output granules of A
    const int nB = B_SZ * WP_SZ * 64;
    int i = blockIdx.x * 256 + threadIdx.x;
    const float* srcrow;
    unsigned char* dst;
    int gran, row;
    if (i < nA) {
        gran = i & 63; row = i >> 6;
        int j = row / RP_SZ, r = row % RP_SZ;
        int rs = r < R_SZ ? r : R_SZ - 1;
        srcrow = im + ((size_t)(j * R_SZ + rs) << 10);
        dst = imb + (size_t)i * 16;
    } else {
        int i2 = i - nA;
        if (i2 >= nB) return;
        gran = i2 & 63; row = i2 >> 6;
        int j = row >> 6, w = row & 63;
        int ws = w < W_SZ ? w : W_SZ - 1;
        srcrow = s + ((size_t)(j * W_SZ + ws) << 10);
        dst = sb + (size_t)i2 * 16;
    }
    const int kb = gran >> 2, g = gran & 3;
    uint4 o;
    unsigned int* op = (unsigned int*)&o;
#pragma unroll
    for (int q = 0; q < 4; ++q) {
        const int kq = kb * 64 + (q >> 1) * 32 + g * 8 + (q & 1) * 4;
        float4 v = *reinterpret_cast<const float4*>(srcrow + kq);
        int w32 = __builtin_amdgcn_cvt_pk_fp8_f32(v.x, v.y, 0, false);
        w32 = __builtin_amdgcn_cvt_pk_fp8_f32(v.z, v.w, w32, true);
        op[q] = (unsigned int)w32;
    }
    *reinterpret_cast<uint4*>(dst) = o;
}

// Fused GEMM + MISA epilogue, fp8-e4m3, R15 structure + mid-window pipeline:
// Block 192x256, BK=64, 8 waves (2Mx4N), per-wave 96x64 (acc[6][4],
// mfma_f32_16x16x32_fp8_fp8). dbuf LDS 56 KB. Zero-conflict slot swizzle
// (R15-validated: slot = (kgrp ^ ((row>>1)&3))*16, both-sides involution).
// Pipeline (fp8 regime: LDS ~640 cyc/tile << MFMA ~1860 -> reads CAN hide):
//   per tile t: MFMA k2=0(f) -> vmcnt(0)+barrier (stage t+1 landed; all
//   reads of buf[t&1] retired via k2=0's operand waits) -> stage t+2 ->
//   issue tile t+1's 10 ds_reads into the OTHER frag set -> sched_barrier ->
//   MFMA k2=1(f). Post-barrier window starts with register-resident MFMAs
//   (no lgkm dependency); the read burst is serviced under 48 MFMAs.
// Two named frag sets (static indexing, rule 20), explicit 2-step unroll.
__global__ __launch_bounds__(512, 2) void scores_kernel(
        const unsigned char* __restrict__ imb,    // [128][48][1024] fp8 interleaved
        const unsigned char* __restrict__ sb,     // [128][64][1024] fp8 interleaved
        const int* __restrict__ s_l,
        float* __restrict__ S)                    // [j][i]
{
    __shared__ __align__(16) unsigned char As[2 * ATILE_B];   // 24 KB
    __shared__ __align__(16) unsigned char Bs[2 * BTILE_B];   // 32 KB

    const int tid  = threadIdx.x;
    const int wid  = tid >> 6;        // 0..7
    const int lane = tid & 63;
    const int l15  = lane & 15;
    const int kgrp = lane >> 4;       // 0..3
    const int wr   = wid >> 2;        // 0..1 (M)
    const int wc   = wid & 3;         // 0..3 (N)

    // Supertile XCD swizzle (R10-validated)
    int bid = blockIdx.x;
    int k8  = bid & 7;                // XCD
    int w   = bid >> 3;               // 0..127 within XCD
    int jtg = w >> 5;                 // 0..3
    int sw  = w & 31;
    int it  = k8 * 4 + (sw >> 3);     // 0..31 (4 captions each)
    int jt  = jtg * 8 + (sw & 7);     // 0..31 (4 images each)

    // staging: chunk = 16 rows x 64 B; row = chunk*16 + lane>>2, dest granule lane&3;
    // source granule = (lane&3) ^ h(row), h(row) = (row>>1)&3 = (lane>>3)&3
    const int drow = lane >> 2;
    const int sgr  = ((lane & 3) ^ ((lane >> 3) & 3)) * 16;

    // 28 1-KB chunks (A:12, B:16); wave w stages chunks {w, w+8, w+16, w+24}
    const unsigned char* gsrc[4];
    unsigned char* gdst0[4];
    int tsz[4];
#pragma unroll
    for (int si = 0; si < 4; ++si) {
        int c = wid + si * 8;
        if (c < 12) {
            gsrc[si]  = imb + (size_t)(jt * 192 + c * 16 + drow) * 1024 + sgr;
            gdst0[si] = As + c * 1024 + lane * 16;
            tsz[si]   = ATILE_B;
        } else if (c < 28) {
            int b = c - 12;
            gsrc[si]  = sb + (size_t)(it * 256 + b * 16 + drow) * 1024 + sgr;
            gdst0[si] = Bs + b * 1024 + lane * 16;
            tsz[si]   = BTILE_B;
        }
    }

    // ds_read addressing: row*64 + (kgrp ^ ((row>>1)&3))*16 (R15, zero-conflict)
    const int slot0 = (kgrp ^ ((l15 >> 1) & 3)) * 16;
    int abase[6];
#pragma unroll
    for (int rf = 0; rf < 6; ++rf)
        abase[rf] = (wr * 96 + rf * 16 + l15) * 64 + slot0;
    int bbase[4];
#pragma unroll
    for (int cf = 0; cf < 4; ++cf)
        bbase[cf] = (wc * 64 + cf * 16 + l15) * 64 + slot0;

    f32x4 acc[6][4] = {};
    longx2 fa[6], fb[4], ga[6], gb[4];   // two frag sets (tile t / t+1)

    // prologue: stage tile 0 -> buf0, tile 1 -> buf1; read tile-0 frags
#pragma unroll
    for (int si = 0; si < 4; ++si) {
        int c = wid + si * 8;
        if (c < 28) gload16(gsrc[si], gdst0[si]);
    }
#pragma unroll
    for (int si = 0; si < 4; ++si) {
        int c = wid + si * 8;
        if (c < 28) gload16(gsrc[si] + 64, gdst0[si] + tsz[si]);
    }
    asm volatile("s_waitcnt vmcnt(7)" ::: "memory");   // tile 0 resident
    __builtin_amdgcn_s_barrier();
#pragma unroll
    for (int rf = 0; rf < 6; ++rf)
        fa[rf] = *reinterpret_cast<const longx2*>(As + abase[rf]);
#pragma unroll
    for (int cf = 0; cf < 4; ++cf)
        fb[cf] = *reinterpret_cast<const longx2*>(Bs + bbase[cf]);

    // one tile step: CA/CB = current frags, NA/NB filled with tile t+1 frags
#define TILE_STEP(t, CA, CB, NA, NB)                                           \
    {                                                                          \
        const int cur = (t) & 1;                                               \
        __builtin_amdgcn_s_setprio(1);                                         \
        _Pragma("unroll")                                                      \
        for (int rf = 0; rf < 6; ++rf)                                         \
            _Pragma("unroll")                                                  \
            for (int cf = 0; cf < 4; ++cf)                                     \
                acc[rf][cf] = __builtin_amdgcn_mfma_f32_16x16x32_fp8_fp8(      \
                    CA[rf][0], CB[cf][0], acc[rf][cf], 0, 0, 0);               \
        __builtin_amdgcn_s_setprio(0);                                         \
        if ((t) < 15) {                                                        \
            asm volatile("s_waitcnt vmcnt(0)" ::: "memory");                   \
            __builtin_amdgcn_s_barrier();                                      \
            const int ko = ((t) + 2 < 16 ? (t) + 2 : 15) * 64;                 \
            _Pragma("unroll")                                                  \
            for (int si = 0; si < 4; ++si) {                                   \
                int c = wid + si * 8;                                          \
                if (c < 28) gload16(gsrc[si] + ko, gdst0[si] + cur * tsz[si]); \
            }                                                                  \
            const unsigned char* An = As + (cur ^ 1) * ATILE_B;                \
            const unsigned char* Bn = Bs + (cur ^ 1) * BTILE_B;                \
            _Pragma("unroll")                                                  \
            for (int rf = 0; rf < 6; ++rf)                                     \
                NA[rf] = *reinterpret_cast<const longx2*>(An + abase[rf]);     \
            _Pragma("unroll")                                                  \
            for (int cf = 0; cf < 4; ++cf)                                     \
                NB[cf] = *reinterpret_cast<const longx2*>(Bn + bbase[cf]);     \
            __builtin_amdgcn_sched_barrier(0);                                 \
        }                                                                      \
        __builtin_amdgcn_s_setprio(1);                                         \
        _Pragma("unroll")                                                      \
        for (int rf = 0; rf < 6; ++rf)                                         \
            _Pragma("unroll")                                                  \
            for (int cf = 0; cf < 4; ++cf)                                     \
                acc[rf][cf] = __builtin_amdgcn_mfma_f32_16x16x32_fp8_fp8(      \
                    CA[rf][1], CB[cf][1], acc[rf][cf], 0, 0, 0);               \
        __builtin_amdgcn_s_setprio(0);                                         \
    }

#pragma unroll 1
    for (int tp = 0; tp < 8; ++tp) {
        TILE_STEP(tp * 2,     fa, fb, ga, gb);
        TILE_STEP(tp * 2 + 1, ga, gb, fa, fb);
    }
#undef TILE_STEP

    // Epilogue: wave (wr,wc) owns caption i = it*4+wc, images j = jt*4 + wr*2 + {0,1}.
    // C frag layout (shape-determined): col = l15 (word), row = kgrp*4 + e (region).
    const int i_cap = it * 4 + wc;
    const int nw = s_l[i_cap];
    const float inv = 1.0f / (float)nw;
#pragma unroll
    for (int h = 0; h < 2; ++h) {       // image half: frags rf = h*3 .. h*3+2 (48 rows)
        float sum = 0.0f;
#pragma unroll
        for (int cf = 0; cf < 4; ++cf) {
            float m = acc[h * 3][cf][0];
#pragma unroll
            for (int rf = h * 3; rf < h * 3 + 3; ++rf)
#pragma unroll
                for (int e = 0; e < 4; ++e)
                    m = fmaxf(m, acc[rf][cf][e]);
            m = fmaxf(m, __shfl_xor(m, 16));
            m = fmaxf(m, __shfl_xor(m, 32));
            int wv = cf * 16 + l15;
            if (wv < nw) sum += m;
        }
        sum += __shfl_xor(sum, 1);
        sum += __shfl_xor(sum, 2);
        sum += __shfl_xor(sum, 4);
        sum += __shfl_xor(sum, 8);
        if (lane == 0) {
            int j_img = jt * 4 + wr * 2 + h;
            S[j_img * B_SZ + i_cap] = sum * inv;
        }
    }
}

// Contrastive loss over the 128x128 score matrix, single block (1024 thr)
__global__ __launch_bounds__(1024) void loss_kernel(
        const float* __restrict__ S, float* __restrict__ out) {
    __shared__ float diag[B_SZ];
    __shared__ float red[1024];
    int t = threadIdx.x;
    if (t < B_SZ) diag[t] = S[t * (B_SZ + 1)];
    __syncthreads();
    float acc = 0.0f;
    for (int idx = t; idx < B_SZ * B_SZ; idx += 1024) {
        int a = idx >> 7, b = idx & (B_SZ - 1);
        if (a != b) {
            float v = S[idx];
            acc += fmaxf(MARGIN + v - diag[a], 0.0f)
                 + fmaxf(MARGIN + v - diag[b], 0.0f);
        }
    }
    red[t] = acc;
    __syncthreads();
    for (int s = 512; s > 0; s >>= 1) {
        if (t < s) red[t] += red[t + s];
        __syncthreads();
    }
    if (t == 0) out[0] = red[0];
}

extern "C" void kernel_launch(void* const* d_in, const int* in_sizes, int n_in,
                              void* d_out, int out_size, void* d_ws, size_t ws_size,
                              hipStream_t stream) {
    const float* im  = (const float*)d_in[0];
    const float* s   = (const float*)d_in[1];
    const int*   s_l = (const int*)d_in[2];
    // d_in[3] (x) unused by the math

    const int n_im_pad = B_SZ * RP_SZ * D_SZ;   // 6,291,456 fp8 bytes
    const int n_s_pad  = B_SZ * WP_SZ * D_SZ;   // 8,388,608 fp8 bytes

    unsigned char* imb = (unsigned char*)d_ws;
    unsigned char* sb  = imb + n_im_pad;
    float* S = (float*)(sb + n_s_pad);          // 128*128 floats

    const int ngran = (n_im_pad + n_s_pad) / 16;   // 16-B granules
    convert_fp8_kernel<<<(ngran + 255) / 256, 256, 0, stream>>>(im, s, imb, sb);

    scores_kernel<<<1024, 512, 0, stream>>>(imb, sb, s_l, S);

    loss_kernel<<<1, 1024, 0, stream>>>(S, (float*)d_out);
}

// Round 17
// 94.141 us; speedup vs baseline: 1.3908x; 1.3908x over previous
//
#include <hip/hip_runtime.h>
#include <hip/hip_bf16.h>
#include <stdint.h>

// Problem dims (fixed by reference setup_inputs)
#define B_SZ 128
#define R_SZ 36       // real regions per image
#define RP_SZ 48      // padded regions (dup row 35) -> multiple of 16
#define W_SZ 60       // real words per caption
#define WP_SZ 64      // padded words (dup word 59, masked in epilogue)
#define D_SZ 1024
#define MARGIN 0.2f

#define ATILE_B (192 * 64)   // BYTES per A K-tile (fp8, BK=64)
#define BTILE_B (256 * 64)   // BYTES per B K-tile

typedef __attribute__((ext_vector_type(4))) float f32x4;    // MFMA C/D frag
typedef __attribute__((ext_vector_type(2))) long longx2;    // one b128 = 2 fp8 frags

typedef __attribute__((address_space(3))) unsigned int lds_u32;
typedef const __attribute__((address_space(1))) unsigned int glb_u32;

__device__ __forceinline__ void gload16(const unsigned char* g, unsigned char* l) {
    __builtin_amdgcn_global_load_lds((glb_u32*)g, (lds_u32*)l, 16, 0, 0);
}

// fp32 -> fp8 e4m3 (HW cvt) + row-pad + K2-INTERLEAVE (validated R14/R15).
// Each 64-B K-block of a row stored as [granule g=kgrp][k2][8B]:
//   out byte g*16 + k2*8 + b  <=  original k = k2*32 + g*8 + b.
__global__ __launch_bounds__(256) void convert_fp8_kernel(
        const float* __restrict__ im, const float* __restrict__ s,
        unsigned char* __restrict__ imb, unsigned char* __restrict__ sb) {
    const int nA = B_SZ * RP_SZ * 64;     // 16-B output granules of A
    const int nB = B_SZ * WP_SZ * 64;
    int i = blockIdx.x * 256 + threadIdx.x;
    const float* srcrow;
    unsigned char* dst;
    int gran, row;
    if (i < nA) {
        gran = i & 63; row = i >> 6;
        int j = row / RP_SZ, r = row % RP_SZ;
        int rs = r < R_SZ ? r : R_SZ - 1;
        srcrow = im + ((size_t)(j * R_SZ + rs) << 10);
        dst = imb + (size_t)i * 16;
    } else {
        int i2 = i - nA;
        if (i2 >= nB) return;
        gran = i2 & 63; row = i2 >> 6;
        int j = row >> 6, w = row & 63;
        int ws = w < W_SZ ? w : W_SZ - 1;
        srcrow = s + ((size_t)(j * W_SZ + ws) << 10);
        dst = sb + (size_t)i2 * 16;
    }
    const int kb = gran >> 2, g = gran & 3;
    uint4 o;
    unsigned int* op = (unsigned int*)&o;
#pragma unroll
    for (int q = 0; q < 4; ++q) {
        const int kq = kb * 64 + (q >> 1) * 32 + g * 8 + (q & 1) * 4;
        float4 v = *reinterpret_cast<const float4*>(srcrow + kq);
        int w32 = __builtin_amdgcn_cvt_pk_fp8_f32(v.x, v.y, 0, false);
        w32 = __builtin_amdgcn_cvt_pk_fp8_f32(v.z, v.w, w32, true);
        op[q] = (unsigned int)w32;
    }
    *reinterpret_cast<uint4*>(dst) = o;
}

// Fused GEMM + MISA epilogue, fp8-e4m3, R15 structure + QUAD-buffer counted
// vmcnt (T3+T4, m218's isolated +38-73% lever, applied correctly at last):
// Block 192x256, BK=64, 8 waves (2Mx4N), per-wave 96x64 (acc[6][4],
// mfma_f32_16x16x32_fp8_fp8). LDS = 4 x 28 KB = 112 KB (1 block/CU).
// Zero-conflict slot swizzle (R15-validated: slot=(kgrp^((row>>1)&3))*16,
// both-sides involution, measured 0 conflicts).
// Per tile u (ONE barrier): stage u+3 -> buf[(u+3)%4] (holds dead tile u-1)
//   -> 10 ds_reads from buf[u%4] -> 48 MFMAs (compiler-counted lgkm)
//   -> s_waitcnt vmcnt(2L) -> s_barrier.
// 2L outstanding = stages of u+2,u+3 still in flight; tile u+1 landed.
// L is per-wave (waves 0-3 stage 4 chunks, 4-7 stage 3): wave-uniform branch
// selects vmcnt(8) / vmcnt(6). Loads fly ~3 windows, NEVER drained to 0.
// Buffer index static: inner 4-step unroll ((g*4+s)%4 == s).
__global__ __launch_bounds__(512, 1) void scores_kernel(
        const unsigned char* __restrict__ imb,    // [128][48][1024] fp8 interleaved
        const unsigned char* __restrict__ sb,     // [128][64][1024] fp8 interleaved
        const int* __restrict__ s_l,
        float* __restrict__ S)                    // [j][i]
{
    __shared__ __align__(16) unsigned char As[4 * ATILE_B];   // 48 KB
    __shared__ __align__(16) unsigned char Bs[4 * BTILE_B];   // 64 KB

    const int tid  = threadIdx.x;
    const int wid  = tid >> 6;        // 0..7
    const int lane = tid & 63;
    const int l15  = lane & 15;
    const int kgrp = lane >> 4;       // 0..3
    const int wr   = wid >> 2;        // 0..1 (M)
    const int wc   = wid & 3;         // 0..3 (N)

    // Supertile XCD swizzle (R10-validated)
    int bid = blockIdx.x;
    int k8  = bid & 7;                // XCD
    int w   = bid >> 3;               // 0..127 within XCD
    int jtg = w >> 5;                 // 0..3
    int sw  = w & 31;
    int it  = k8 * 4 + (sw >> 3);     // 0..31 (4 captions each)
    int jt  = jtg * 8 + (sw & 7);     // 0..31 (4 images each)

    // staging: chunk = 16 rows x 64 B; row = chunk*16 + lane>>2, dest granule lane&3;
    // source granule = (lane&3) ^ h(row), h(row) = (row>>1)&3 = (lane>>3)&3
    const int drow = lane >> 2;
    const int sgr  = ((lane & 3) ^ ((lane >> 3) & 3)) * 16;

    // 28 1-KB chunks (A:12, B:16); wave w stages chunks {w, w+8, w+16, w+24}
    const unsigned char* gsrc[4];
    unsigned char* gdst0[4];
    int tsz[4];
#pragma unroll
    for (int si = 0; si < 4; ++si) {
        int c = wid + si * 8;
        if (c < 12) {
            gsrc[si]  = imb + (size_t)(jt * 192 + c * 16 + drow) * 1024 + sgr;
            gdst0[si] = As + c * 1024 + lane * 16;
            tsz[si]   = ATILE_B;
        } else if (c < 28) {
            int b = c - 12;
            gsrc[si]  = sb + (size_t)(it * 256 + b * 16 + drow) * 1024 + sgr;
            gdst0[si] = Bs + b * 1024 + lane * 16;
            tsz[si]   = BTILE_B;
        }
    }

    // ds_read addressing: row*64 + (kgrp ^ ((row>>1)&3))*16 (R15, zero-conflict)
    const int slot0 = (kgrp ^ ((l15 >> 1) & 3)) * 16;
    int abase[6];
#pragma unroll
    for (int rf = 0; rf < 6; ++rf)
        abase[rf] = (wr * 96 + rf * 16 + l15) * 64 + slot0;
    int bbase[4];
#pragma unroll
    for (int cf = 0; cf < 4; ++cf)
        bbase[cf] = (wc * 64 + cf * 16 + l15) * 64 + slot0;

    f32x4 acc[6][4] = {};

    // prologue: stage tiles 0,1,2 into buffers 0,1,2; wait t0 (2L left), barrier
#pragma unroll
    for (int b = 0; b < 3; ++b)
#pragma unroll
        for (int si = 0; si < 4; ++si) {
            int c = wid + si * 8;
            if (c < 28) gload16(gsrc[si] + b * 64, gdst0[si] + b * tsz[si]);
        }
    if (wid < 4) { asm volatile("s_waitcnt vmcnt(8)" ::: "memory"); }
    else         { asm volatile("s_waitcnt vmcnt(6)" ::: "memory"); }
    __builtin_amdgcn_s_barrier();

#pragma unroll 1
    for (int g = 0; g < 4; ++g) {
#pragma unroll
        for (int s = 0; s < 4; ++s) {
            const int u  = g * 4 + s;     // tile index (s static -> bufs static)
            const int rb = s;             // u % 4 : read buffer
            const int sb4 = (s + 3) & 3;  // (u+3) % 4 : stage buffer (holds dead u-1)

            // stage tile u+3 (clamped; tail stages are redundant, counts uniform)
            const int ko = (u + 3 < 16 ? u + 3 : 15) * 64;
#pragma unroll
            for (int si = 0; si < 4; ++si) {
                int c = wid + si * 8;
                if (c < 28) gload16(gsrc[si] + ko, gdst0[si] + sb4 * tsz[si]);
            }

            // 10 ds_read_b128 from buf[rb] (each = both k2 frags)
            const unsigned char* Ac = As + rb * ATILE_B;
            const unsigned char* Bc = Bs + rb * BTILE_B;
            longx2 afr[6], bfr[4];
#pragma unroll
            for (int rf = 0; rf < 6; ++rf)
                afr[rf] = *reinterpret_cast<const longx2*>(Ac + abase[rf]);
#pragma unroll
            for (int cf = 0; cf < 4; ++cf)
                bfr[cf] = *reinterpret_cast<const longx2*>(Bc + bbase[cf]);

            // 48 MFMAs (compiler-counted lgkm waits interleave reads under MFMAs)
            __builtin_amdgcn_s_setprio(1);
#pragma unroll
            for (int k2 = 0; k2 < 2; ++k2)
#pragma unroll
                for (int rf = 0; rf < 6; ++rf)
#pragma unroll
                    for (int cf = 0; cf < 4; ++cf)
                        acc[rf][cf] = __builtin_amdgcn_mfma_f32_16x16x32_fp8_fp8(
                            afr[rf][k2], bfr[cf][k2], acc[rf][cf], 0, 0, 0);
            __builtin_amdgcn_s_setprio(0);

            // counted rendezvous: <=2L outstanding (u+2,u+3) => u+1 landed
            if (u < 15) {
                if (wid < 4) { asm volatile("s_waitcnt vmcnt(8)" ::: "memory"); }
                else         { asm volatile("s_waitcnt vmcnt(6)" ::: "memory"); }
                __builtin_amdgcn_s_barrier();
            }
        }
    }

    // Epilogue: wave (wr,wc) owns caption i = it*4+wc, images j = jt*4 + wr*2 + {0,1}.
    // C frag layout (shape-determined): col = l15 (word), row = kgrp*4 + e (region).
    const int i_cap = it * 4 + wc;
    const int nw = s_l[i_cap];
    const float inv = 1.0f / (float)nw;
#pragma unroll
    for (int h = 0; h < 2; ++h) {       // image half: frags rf = h*3 .. h*3+2 (48 rows)
        float sum = 0.0f;
#pragma unroll
        for (int cf = 0; cf < 4; ++cf) {
            float m = acc[h * 3][cf][0];
#pragma unroll
            for (int rf = h * 3; rf < h * 3 + 3; ++rf)
#pragma unroll
                for (int e = 0; e < 4; ++e)
                    m = fmaxf(m, acc[rf][cf][e]);
            m = fmaxf(m, __shfl_xor(m, 16));
            m = fmaxf(m, __shfl_xor(m, 32));
            int wv = cf * 16 + l15;
            if (wv < nw) sum += m;
        }
        sum += __shfl_xor(sum, 1);
        sum += __shfl_xor(sum, 2);
        sum += __shfl_xor(sum, 4);
        sum += __shfl_xor(sum, 8);
        if (lane == 0) {
            int j_img = jt * 4 + wr * 2 + h;
            S[j_img * B_SZ + i_cap] = sum * inv;
        }
    }
}

// Contrastive loss over the 128x128 score matrix, single block (1024 thr)
__global__ __launch_bounds__(1024) void loss_kernel(
        const float* __restrict__ S, float* __restrict__ out) {
    __shared__ float diag[B_SZ];
    __shared__ float red[1024];
    int t = threadIdx.x;
    if (t < B_SZ) diag[t] = S[t * (B_SZ + 1)];
    __syncthreads();
    float acc = 0.0f;
    for (int idx = t; idx < B_SZ * B_SZ; idx += 1024) {
        int a = idx >> 7, b = idx & (B_SZ - 1);
        if (a != b) {
            float v = S[idx];
            acc += fmaxf(MARGIN + v - diag[a], 0.0f)
                 + fmaxf(MARGIN + v - diag[b], 0.0f);
        }
    }
    red[t] = acc;
    __syncthreads();
    for (int s = 512; s > 0; s >>= 1) {
        if (t < s) red[t] += red[t + s];
        __syncthreads();
    }
    if (t == 0) out[0] = red[0];
}

extern "C" void kernel_launch(void* const* d_in, const int* in_sizes, int n_in,
                              void* d_out, int out_size, void* d_ws, size_t ws_size,
                              hipStream_t stream) {
    const float* im  = (const float*)d_in[0];
    const float* s   = (const float*)d_in[1];
    const int*   s_l = (const int*)d_in[2];
    // d_in[3] (x) unused by the math

    const int n_im_pad = B_SZ * RP_SZ * D_SZ;   // 6,291,456 fp8 bytes
    const int n_s_pad  = B_SZ * WP_SZ * D_SZ;   // 8,388,608 fp8 bytes

    unsigned char* imb = (unsigned char*)d_ws;
    unsigned char* sb  = imb + n_im_pad;
    float* S = (float*)(sb + n_s_pad);          // 128*128 floats

    const int ngran = (n_im_pad + n_s_pad) / 16;   // 16-B granules
    convert_fp8_kernel<<<(ngran + 255) / 256, 256, 0, stream>>>(im, s, imb, sb);

    scores_kernel<<<1024, 512, 0, stream>>>(imb, sb, s_l, S);

    loss_kernel<<<1, 1024, 0, stream>>>(S, (float*)d_out);
}